// Round 1
// baseline (1178.676 us; speedup 1.0000x reference)
//
#include <hip/hip_runtime.h>
#include <stdint.h>

// ---------------------------------------------------------------------------
// out = x @ nf4_quant_dequant(w).T
//   x: [M=16384, K=4096] fp32,  w: [N=4096, K=4096] fp32,  out: [M, N] fp32
// Plan: (1) fake-quant w -> bf16 in ws, (2) cast x -> bf16 in ws,
//       (3) bf16 MFMA GEMM (m97 structure: 128x128 tile, BK=32,
//           global_load_lds width=16, 4 waves x 4x4 acc of 16x16x32 MFMA).
// ws usage: w_bf16 (33.5 MB) + x_bf16 (134 MB) = 168 MB.
// ---------------------------------------------------------------------------

typedef __bf16 bf16x8 __attribute__((ext_vector_type(8)));
typedef float f32x4 __attribute__((ext_vector_type(4)));

// NF4 codebook (exact fp32 values) + midpoint boundaries (compile-time fp32).
constexpr float NF4_CODE[16] = {
    -1.0f, -0.6961928009986877f, -0.5250730514526367f, -0.39491748809814453f,
    -0.28444138169288635f, -0.18477343022823334f, -0.09105003625154495f, 0.0f,
    0.07958029955625534f, 0.16093020141124725f, 0.24611230194568634f,
    0.33791524171829224f, 0.44070982933044434f, 0.5626170039176941f,
    0.7229568362236023f, 1.0f};
constexpr float NF4_BND[15] = {
    0.5f * (NF4_CODE[0] + NF4_CODE[1]),   0.5f * (NF4_CODE[1] + NF4_CODE[2]),
    0.5f * (NF4_CODE[2] + NF4_CODE[3]),   0.5f * (NF4_CODE[3] + NF4_CODE[4]),
    0.5f * (NF4_CODE[4] + NF4_CODE[5]),   0.5f * (NF4_CODE[5] + NF4_CODE[6]),
    0.5f * (NF4_CODE[6] + NF4_CODE[7]),   0.5f * (NF4_CODE[7] + NF4_CODE[8]),
    0.5f * (NF4_CODE[8] + NF4_CODE[9]),   0.5f * (NF4_CODE[9] + NF4_CODE[10]),
    0.5f * (NF4_CODE[10] + NF4_CODE[11]), 0.5f * (NF4_CODE[11] + NF4_CODE[12]),
    0.5f * (NF4_CODE[12] + NF4_CODE[13]), 0.5f * (NF4_CODE[13] + NF4_CODE[14]),
    0.5f * (NF4_CODE[14] + NF4_CODE[15])};

__device__ __forceinline__ unsigned short f2bf(float f) {
  // RNE fp32 -> bf16 (inputs are finite; no NaN handling needed)
  unsigned int u = __float_as_uint(f);
  u += 0x7fffu + ((u >> 16) & 1u);
  return (unsigned short)(u >> 16);
}

// ---------------------------------------------------------------------------
// Kernel 1: NF4 fake quant-dequant of weights, fp32 -> bf16 bits.
// One 256-thread block per scale superblock (256 quant blocks of 64 = 16384
// consecutive weights = 4 rows). Thread t owns quant block t (64 weights).
// ---------------------------------------------------------------------------
__global__ __launch_bounds__(256) void nf4_dequant(const float* __restrict__ w,
                                                   unsigned short* __restrict__ wdq) {
  __shared__ float s_am[256];
  __shared__ float s_code[16];
  const int t = threadIdx.x;
  if (t < 16) s_code[t] = NF4_CODE[t];

  const size_t base = (size_t)blockIdx.x * 16384 + (size_t)t * 64;
  const float4* src = (const float4*)(w + base);
  float4 v[16];
  float amax = 0.f;
#pragma unroll
  for (int i = 0; i < 16; ++i) {
    v[i] = src[i];
    amax = fmaxf(amax, fmaxf(fmaxf(fabsf(v[i].x), fabsf(v[i].y)),
                             fmaxf(fabsf(v[i].z), fabsf(v[i].w))));
  }
  s_am[t] = amax;
  __syncthreads();
#pragma unroll
  for (int off = 128; off > 0; off >>= 1) {
    if (t < off) s_am[t] = fmaxf(s_am[t], s_am[t + off]);
    __syncthreads();
  }
  const float s_amax = s_am[0];
  const float sa = (s_amax == 0.f) ? 1.f : s_amax;  // safe superblock absmax
  // 8-bit symmetric double quant of the per-block scale (RNE like jnp.round)
  float q8 = rintf(amax / sa * 127.f);
  q8 = fminf(fmaxf(q8, -127.f), 127.f);
  const float scale = (q8 / 127.f) * sa;            // dequantized block scale
  const float safe_am = (amax == 0.f) ? 1.f : amax;

  auto dq1 = [&](float x) -> unsigned short {
    const float norm = x / safe_am;                 // in [-1, 1]
    int idx = 0;                                    // searchsorted(side='left')
#pragma unroll
    for (int j = 0; j < 15; ++j) idx += (NF4_BND[j] < norm) ? 1 : 0;
    return f2bf(s_code[idx] * scale);
  };

  uint4* dst = (uint4*)(wdq + base);
#pragma unroll
  for (int i = 0; i < 8; ++i) {
    const float4 a = v[2 * i], b = v[2 * i + 1];
    uint4 o;
    o.x = (unsigned)dq1(a.x) | ((unsigned)dq1(a.y) << 16);
    o.y = (unsigned)dq1(a.z) | ((unsigned)dq1(a.w) << 16);
    o.z = (unsigned)dq1(b.x) | ((unsigned)dq1(b.y) << 16);
    o.w = (unsigned)dq1(b.z) | ((unsigned)dq1(b.w) << 16);
    dst[i] = o;
  }
}

// ---------------------------------------------------------------------------
// Kernel 2: cast x fp32 -> bf16 bits (8 elements / thread, fully coalesced)
// ---------------------------------------------------------------------------
__global__ __launch_bounds__(256) void cast_f32_to_bf16(const float* __restrict__ x,
                                                        unsigned short* __restrict__ y,
                                                        size_t n8) {
  const size_t i = (size_t)blockIdx.x * 256 + threadIdx.x;
  if (i >= n8) return;
  const float4* s = (const float4*)x + i * 2;
  const float4 a = s[0], b = s[1];
  uint4 o;
  o.x = (unsigned)f2bf(a.x) | ((unsigned)f2bf(a.y) << 16);
  o.y = (unsigned)f2bf(a.z) | ((unsigned)f2bf(a.w) << 16);
  o.z = (unsigned)f2bf(b.x) | ((unsigned)f2bf(b.y) << 16);
  o.w = (unsigned)f2bf(b.z) | ((unsigned)f2bf(b.w) << 16);
  ((uint4*)y)[i] = o;
}

// ---------------------------------------------------------------------------
// Kernel 3: C[M,N] = A[M,K] * Bt[N,K]^T, bf16 inputs, fp32 out.
// 128x128 tile, BK=32, 256 threads (4 waves, 2x2), each wave 64x64 via
// 4x4 grid of v_mfma_f32_16x16x32_bf16. Staging via global_load_lds (16B).
// ---------------------------------------------------------------------------
#define BM 128
#define BN 128
#define BK 32

__device__ __forceinline__ void load_lds16(const unsigned short* g, unsigned short* l) {
  __builtin_amdgcn_global_load_lds(
      (__attribute__((address_space(1))) void*)g,
      (__attribute__((address_space(3))) void*)l, 16, 0, 0);
}

__global__ __launch_bounds__(256) void gemm_bf16_bt(const unsigned short* __restrict__ A,
                                                    const unsigned short* __restrict__ Bt,
                                                    float* __restrict__ C,
                                                    int M, int N, int K) {
  // LDS tiles, row-major [rows][BK], 16B chunk c <-> (row=c>>2, kgroup=c&3).
  // ds_read_b128 frag pattern is bank-balanced (8 cycles structural min).
  __shared__ __align__(16) unsigned short sA[BM * BK];
  __shared__ __align__(16) unsigned short sB[BN * BK];

  const int t = threadIdx.x;
  const int wave = t >> 6;
  const int lane = t & 63;
  const int bm = blockIdx.y * BM;
  const int bn = blockIdx.x * BN;

  // --- staging addressing: wave handles chunks [wave*128, wave*128+128),
  // two issues (q=0,1) of 64 chunks; lane's global src row/col:
  const int kg = lane & 3;                 // 8-elem k-group within BK
  const int r0 = wave * 32 + (lane >> 2);  // tile row for q=0 (q=1: +16)
  const unsigned short* gA0 = A + (size_t)(bm + r0) * K + kg * 8;
  const unsigned short* gA1 = A + (size_t)(bm + r0 + 16) * K + kg * 8;
  const unsigned short* gB0 = Bt + (size_t)(bn + r0) * K + kg * 8;
  const unsigned short* gB1 = Bt + (size_t)(bn + r0 + 16) * K + kg * 8;
  unsigned short* lA0 = sA + (size_t)(wave * 128) * 8;        // wave-uniform
  unsigned short* lA1 = sA + (size_t)(wave * 128 + 64) * 8;
  unsigned short* lB0 = sB + (size_t)(wave * 128) * 8;
  unsigned short* lB1 = sB + (size_t)(wave * 128 + 64) * 8;

  // --- compute addressing: wave (2x2), 4x4 16x16 tiles of 64x64.
  const int quad = lane >> 4;
  const int lrow = lane & 15;
  const int wm = (wave >> 1) * 64;
  const int wn = (wave & 1) * 64;
  int aoff[4], boff[4];
#pragma unroll
  for (int i = 0; i < 4; ++i) {
    aoff[i] = (wm + i * 16 + lrow) * BK + quad * 8;  // A[m=lrow][k=quad*8+j]
    boff[i] = (wn + i * 16 + lrow) * BK + quad * 8;  // Bt[n=lrow][k=quad*8+j]
  }

  f32x4 acc[4][4];
  const f32x4 zero = {0.f, 0.f, 0.f, 0.f};
#pragma unroll
  for (int i = 0; i < 4; ++i)
#pragma unroll
    for (int j = 0; j < 4; ++j) acc[i][j] = zero;

  for (int k0 = 0; k0 < K; k0 += BK) {
    __syncthreads();  // LDS reuse guard
    load_lds16(gA0 + k0, lA0);
    load_lds16(gA1 + k0, lA1);
    load_lds16(gB0 + k0, lB0);
    load_lds16(gB1 + k0, lB1);
    __syncthreads();  // drains vmcnt (global_load_lds) + lgkm

    bf16x8 af[4], bf[4];
#pragma unroll
    for (int i = 0; i < 4; ++i) af[i] = *(const bf16x8*)(sA + aoff[i]);
#pragma unroll
    for (int j = 0; j < 4; ++j) bf[j] = *(const bf16x8*)(sB + boff[j]);
#pragma unroll
    for (int i = 0; i < 4; ++i)
#pragma unroll
      for (int j = 0; j < 4; ++j)
        acc[i][j] = __builtin_amdgcn_mfma_f32_16x16x32_bf16(af[i], bf[j], acc[i][j], 0, 0, 0);
  }

  // epilogue: D[row=quad*4+r][col=lrow] per 16x16 tile
#pragma unroll
  for (int i = 0; i < 4; ++i) {
    const int row = bm + wm + i * 16 + quad * 4;
#pragma unroll
    for (int j = 0; j < 4; ++j) {
      const int col = bn + wn + j * 16 + lrow;
      float* cp = C + (size_t)row * N + col;
#pragma unroll
      for (int r = 0; r < 4; ++r) cp[(size_t)r * N] = acc[i][j][r];
    }
  }
}

// ---------------------------------------------------------------------------
extern "C" void kernel_launch(void* const* d_in, const int* in_sizes, int n_in,
                              void* d_out, int out_size, void* d_ws, size_t ws_size,
                              hipStream_t stream) {
  const float* x = (const float*)d_in[0];   // [M, K]
  const float* w = (const float*)d_in[1];   // [N, K]
  const int K = 4096;
  const int M = in_sizes[0] / K;            // 16384
  const int N = in_sizes[1] / K;            // 4096

  unsigned short* wdq = (unsigned short*)d_ws;            // [N*K] bf16 bits
  unsigned short* xbf = wdq + (size_t)in_sizes[1];        // [M*K] bf16 bits
  // needs ws_size >= 2*(in_sizes[0]+in_sizes[1]) = 168 MB

  nf4_dequant<<<in_sizes[1] / 16384, 256, 0, stream>>>(w, wdq);
  cast_f32_to_bf16<<<((size_t)in_sizes[0] / 8 + 255) / 256, 256, 0, stream>>>(
      x, xbf, (size_t)in_sizes[0] / 8);
  dim3 grid(N / BN, M / BM);
  gemm_bf16_bt<<<grid, 256, 0, stream>>>(xbf, wdq, (float*)d_out, M, N, K);
}